// Round 6
// baseline (8713.708 us; speedup 1.0000x reference)
//
#include <hip/hip_runtime.h>
#include <hip/hip_bf16.h>

typedef _Float16 half8 __attribute__((ext_vector_type(8)));
typedef _Float16 half4v __attribute__((ext_vector_type(4)));
typedef float f32x4 __attribute__((ext_vector_type(4)));

#define BB 64
#define SS 512
#define HH 1024
#define G4 4096
#define NSTEP 514
#define SLOT 65536  // elements per h matrix (64*1024 fp16 = 131072 B)

// SAFE-mode barrier words (round-3 layout)
#define SB_ARR(g) ((g) * 32)
#define SB_GLB 256
#define SB_GO(g) (288 + (g) * 32)
// FUSED-mode barrier words: single barrier, 8 groups
#define FU_ARR(g) ((g) * 32)
#define FU_GLB 256
#define FU_GO(g) (288 + (g) * 32)

__device__ __forceinline__ float sigmf(float x) { return 1.0f / (1.0f + __expf(-x)); }
__device__ __forceinline__ float tanhfast(float x) { return 2.0f / (1.0f + __expf(-2.0f * x)) - 1.0f; }

__device__ __forceinline__ unsigned aload(const unsigned* p) {
  return __hip_atomic_load(p, __ATOMIC_RELAXED, __HIP_MEMORY_SCOPE_AGENT);
}
__device__ __forceinline__ void wait_ge(const unsigned* p, unsigned tgt) {
  while (aload(p) < tgt) __builtin_amdgcn_s_sleep(4);  // ~256cy backoff: cut poll traffic
}
__device__ __forceinline__ unsigned aadd(unsigned* p) {
  return __hip_atomic_fetch_add(p, 1u, __ATOMIC_RELAXED, __HIP_MEMORY_SCOPE_AGENT);
}
__device__ __forceinline__ void astore(unsigned* p, unsigned v) {
  __hip_atomic_store(p, v, __ATOMIC_RELAXED, __HIP_MEMORY_SCOPE_AGENT);
}

// inputs[b][s][h] (f32) -> x16[s][b][h] (fp16), time-major
__global__ __launch_bounds__(256) void convert_x_kernel(const float* __restrict__ in,
                                                        _Float16* __restrict__ x16) {
  size_t idx = (size_t)blockIdx.x * 256 + threadIdx.x;
  int h4 = (int)(idx & 255);
  int s  = (int)((idx >> 8) & 511);
  int b  = (int)(idx >> 17);
  const float4* src = (const float4*)in;
  float4 v = src[((size_t)b * SS + s) * 256 + h4];
  half4v hv = { (_Float16)v.x, (_Float16)v.y, (_Float16)v.z, (_Float16)v.w };
  *(half4v*)(x16 + ((size_t)s * BB + b) * HH + (size_t)h4 * 4) = hv;
}

// W[l][k][n] (f32) -> wT[m][n][k] (fp16); m: 0=Wx l0, 1=Wx l1, 2=Wh l0, 3=Wh l1
__global__ __launch_bounds__(256) void convert_w_kernel(const float* __restrict__ Wx,
                                                        const float* __restrict__ Wh,
                                                        _Float16* __restrict__ wT) {
  __shared__ float tile[32][33];
  int m = blockIdx.x >> 12;
  int t = blockIdx.x & 4095;
  int tn = t & 127, tk = t >> 7;
  int l = m & 1, which = m >> 1;
  const float* src = (which ? Wh : Wx) + (size_t)l * HH * G4;
  int tx = threadIdx.x & 31, ty = threadIdx.x >> 5;
#pragma unroll
  for (int p = 0; p < 4; ++p) {
    int k = tk * 32 + ty + 8 * p, n = tn * 32 + tx;
    tile[ty + 8 * p][tx] = src[(size_t)k * G4 + n];
  }
  __syncthreads();
  _Float16* dst = wT + (size_t)m * G4 * HH;
#pragma unroll
  for (int p = 0; p < 4; ++p) {
    int n = tn * 32 + ty + 8 * p, k = tk * 32 + tx;
    dst[(size_t)n * HH + k] = (_Float16)tile[tx][ty + 8 * p];
  }
}

// FUSED persistent LSTM: 128 blocks x 512 threads, 1 block/CU (91KB LDS).
// Block j owns h-cols [8j,8j+8) of BOTH layers. Waves 0-3: layer1 step t
// (K-split 4 x 256); waves 4-7: layer2 step t-2. ONE barrier per timestep,
// 128 pollers with s_sleep(4) backoff -> ~8x less coherence-point poll traffic
// than R5 (2 barriers, 256 pollers, sleep(1)).
// Trajectory h slots (freshness-by-construction, no acquire fences) as in R5.
// Barrier invariants: uniform tmax; unconditional wait BEFORE arrive.
__global__ __launch_bounds__(512, 2) void lstm_fused(
    const _Float16* __restrict__ x16, const _Float16* __restrict__ wT,
    const float* __restrict__ bx, const float* __restrict__ bh,
    _Float16* __restrict__ h1buf, _Float16* __restrict__ h2buf,
    float* __restrict__ hmax, unsigned* __restrict__ bar) {
  __shared__ float part[8][32][72];  // [wave][col][row+pad] = 73,728 B (ww0-3=L1, 4-7=L2)
  __shared__ float red[64][68];      // [row][col: 0-31 L1, 32-63 L2]  = 17,408 B

  const int bid = blockIdx.x;        // 0..127
  const int j = bid;
  const int tid = threadIdx.x;
  const int w = tid >> 6, l = tid & 63;
  const int l15 = l & 15, lg = l >> 4;
  const int grp = bid & 7;
  const int wlayer = w >> 2;         // this wave's layer
  const int kbase = (w & 3) * 256;   // K-slice [kbase, kbase+256)

  // ---- one-time: weight fragments into registers (one layer, K=256) ----
  const _Float16* wTe = wT + (size_t)wlayer * G4 * HH;        // Wx
  const _Float16* wTr = wT + (size_t)(2 + wlayer) * G4 * HH;  // Wh
  half8 Be[16], Br[16];              // [kk 0..7][c 0..1] : 128 VGPRs
#pragma unroll
  for (int kk = 0; kk < 8; ++kk)
#pragma unroll
    for (int c = 0; c < 2; ++c) {
      int nl = 16 * c + l15;
      size_t gcol = (size_t)((nl & 3) * HH + 8 * j + (nl >> 2));
      Be[kk * 2 + c] = *(const half8*)(wTe + gcol * HH + kbase + 32 * kk + 8 * lg);
      Br[kk * 2 + c] = *(const half8*)(wTr + gcol * HH + kbase + 32 * kk + 8 * lg);
    }

  // ---- per-thread epilogue state: threads 0-255 -> L1, 256-511 -> L2 ----
  const int elayer = tid >> 8;
  const int erow = (tid & 255) >> 2, m2 = tid & 3;
  const int hc0 = 8 * j + 2 * m2;
  float bs[8];
  float c0 = 0.f, c1 = 0.f, hm0 = -2.f, hm1 = -2.f;
#pragma unroll
  for (int dm = 0; dm < 2; ++dm)
#pragma unroll
    for (int g = 0; g < 4; ++g)
      bs[4 * dm + g] = bx[elayer * G4 + g * HH + hc0 + dm] + bh[elayer * G4 + g * HH + hc0 + dm];

#pragma unroll 1
  for (int t = 0; t < NSTEP; ++t) {
    const bool wact = wlayer ? (t >= 2) : (t < SS);  // t<514 implicit for L2
    f32x4 acc[8];
#pragma unroll
    for (int i = 0; i < 8; ++i) acc[i] = (f32x4){0.f, 0.f, 0.f, 0.f};

    // ---- Phase A (pre-detect): input half.
    // L1: x[t] @ Wx1 (static).  L2: h1[t-2] (slot t-1, released at barrier t-2,
    // detected at our iter t-1 wait) @ Wx2.
    if (wact) {
      const _Float16* Ae = (wlayer == 0) ? x16 + (size_t)t * SLOT
                                         : h1buf + (size_t)(t - 1) * SLOT;
      const _Float16* aep = Ae + (size_t)l15 * HH + kbase + 8 * lg;
#pragma unroll
      for (int rf = 0; rf < 4; ++rf) {
        half8 av[8];
#pragma unroll
        for (int kk = 0; kk < 8; ++kk)
          av[kk] = *(const half8*)(aep + (size_t)(16 * rf) * HH + 32 * kk);
#pragma unroll
        for (int kk = 0; kk < 8; ++kk) {
          acc[rf * 2 + 0] = __builtin_amdgcn_mfma_f32_16x16x32_f16(av[kk], Be[kk * 2 + 0], acc[rf * 2 + 0], 0, 0, 0);
          acc[rf * 2 + 1] = __builtin_amdgcn_mfma_f32_16x16x32_f16(av[kk], Be[kk * 2 + 1], acc[rf * 2 + 1], 0, 0, 0);
        }
      }
    }

    // ---- Phase B: single barrier wait (unconditional; ordered arrivals) ----
    if (tid == 0) wait_ge(bar + FU_GO(grp), (unsigned)t);
    __syncthreads();

    // ---- Phase C: recurrent half. L1: h1[t-1] (slot t). L2: h2[t-3] (slot t-2).
    if (wact) {
      const _Float16* Ah = (wlayer == 0) ? h1buf + (size_t)t * SLOT
                                         : h2buf + (size_t)(t - 2) * SLOT;
      const _Float16* ahp = Ah + (size_t)l15 * HH + kbase + 8 * lg;
#pragma unroll
      for (int rf = 0; rf < 4; ++rf) {
        half8 av[8];
#pragma unroll
        for (int kk = 0; kk < 8; ++kk)
          av[kk] = *(const half8*)(ahp + (size_t)(16 * rf) * HH + 32 * kk);
#pragma unroll
        for (int kk = 0; kk < 8; ++kk) {
          acc[rf * 2 + 0] = __builtin_amdgcn_mfma_f32_16x16x32_f16(av[kk], Br[kk * 2 + 0], acc[rf * 2 + 0], 0, 0, 0);
          acc[rf * 2 + 1] = __builtin_amdgcn_mfma_f32_16x16x32_f16(av[kk], Br[kk * 2 + 1], acc[rf * 2 + 1], 0, 0, 0);
        }
      }
#pragma unroll
      for (int rf = 0; rf < 4; ++rf)
#pragma unroll
        for (int c = 0; c < 2; ++c)
          *(f32x4*)&part[w][16 * c + l15][16 * rf + 4 * lg] = acc[rf * 2 + c];
    }
    __syncthreads();

    // ---- gather: 1024 slots (2 layers x 32 cols x 16 row-quads), 2 per thread
#pragma unroll
    for (int sidx = 0; sidx < 2; ++sidx) {
      int s = tid + 512 * sidx;
      int L = s >> 9, col = (s >> 4) & 31, rq = s & 15;
      f32x4 sum = {0.f, 0.f, 0.f, 0.f};
#pragma unroll
      for (int ww = 0; ww < 4; ++ww)
        sum += *(const f32x4*)&part[4 * L + ww][col][4 * rq];
      red[4 * rq + 0][col + 32 * L] = sum[0];
      red[4 * rq + 1][col + 32 * L] = sum[1];
      red[4 * rq + 2][col + 32 * L] = sum[2];
      red[4 * rq + 3][col + 32 * L] = sum[3];
    }
    __syncthreads();

    // ---- epilogue: thread handles (layer=elayer, row=erow, hcols hc0,hc0+1)
    const bool eact = elayer ? (t >= 2) : (t < SS);
    if (eact) {
      float v[8];
#pragma unroll
      for (int q = 0; q < 8; ++q) v[q] = red[erow][32 * elayer + 8 * m2 + q] + bs[q];
      float i0 = sigmf(v[0]), f0 = sigmf(v[1]), g0 = tanhfast(v[2]), o0 = sigmf(v[3]);
      float i1 = sigmf(v[4]), f1 = sigmf(v[5]), g1 = tanhfast(v[6]), o1 = sigmf(v[7]);
      c0 = f0 * c0 + i0 * g0;
      c1 = f1 * c1 + i1 * g1;
      float h0 = tanhfast(c0) * o0;
      float h1 = tanhfast(c1) * o1;
      if (elayer == 1) { hm0 = fmaxf(hm0, h0); hm1 = fmaxf(hm1, h1); }
      _Float16* hout = (elayer == 0) ? h1buf + (size_t)(t + 1) * SLOT   // h1[t] -> slot t+1
                                     : h2buf + (size_t)(t - 1) * SLOT;  // h2[t-2] -> slot t-1
      unsigned pk = ((unsigned)__builtin_bit_cast(unsigned short, (_Float16)h1) << 16) |
                    (unsigned)__builtin_bit_cast(unsigned short, (_Float16)h0);
      astore((unsigned*)hout + ((erow * HH + hc0) >> 1), pk);  // sc1 write-through
    }

    // ---- arrive (syncthreads drains all waves' publishes first) ----
    __syncthreads();
    if (tid == 0) {
      unsigned prev = aadd(bar + FU_ARR(grp));
      if (prev == 16u * (unsigned)(t + 1) - 1u) {
        unsigned p2 = aadd(bar + FU_GLB);
        if (p2 == 8u * (unsigned)(t + 1) - 1u) {
#pragma unroll
          for (int gg = 0; gg < 8; ++gg)
            astore(bar + FU_GO(gg), (unsigned)(t + 1));
        }
      }
    }
  }

  if (tid >= 256) {
    hmax[erow * HH + hc0]     = hm0;
    hmax[erow * HH + hc0 + 1] = hm1;
  }
}

// SAFE fallback (round-3 proven): rings + per-step acquire fence, 256 blocks.
__global__ __launch_bounds__(512, 2) void lstm_safe(
    const _Float16* __restrict__ x16, const _Float16* __restrict__ wT,
    const float* __restrict__ bx, const float* __restrict__ bh,
    _Float16* __restrict__ h1buf, _Float16* __restrict__ h2buf,
    float* __restrict__ hmax, unsigned* __restrict__ bar) {
  __shared__ float part[8][32][72];
  __shared__ float red[64][37];

  const int bid = blockIdx.x;
  const int layer = bid >> 7;
  const int j = bid & 127;
  const int tid = threadIdx.x;
  const int w = tid >> 6, l = tid & 63;
  const int l15 = l & 15, lg = l >> 4;
  const int grp = bid & 7;

  const _Float16* wTe = wT + (size_t)layer * G4 * HH;
  const _Float16* wTr = wT + (size_t)(2 + layer) * G4 * HH;
  const int kbase = w * 128;
  half8 Be[8], Br[8];
#pragma unroll
  for (int kk = 0; kk < 4; ++kk)
#pragma unroll
    for (int c = 0; c < 2; ++c) {
      int nl = 16 * c + l15;
      size_t gcol = (size_t)((nl & 3) * HH + 8 * j + (nl >> 2));
      Be[kk * 2 + c] = *(const half8*)(wTe + gcol * HH + kbase + 32 * kk + 8 * lg);
      Br[kk * 2 + c] = *(const half8*)(wTr + gcol * HH + kbase + 32 * kk + 8 * lg);
    }

  const int erow = tid >> 2, m2 = tid & 3;
  const int hc0 = 8 * j + 2 * m2;
  float bs[8];
  float c0 = 0.f, c1 = 0.f, hm0 = -2.f, hm1 = -2.f;
  if (tid < 256) {
#pragma unroll
    for (int dm = 0; dm < 2; ++dm)
#pragma unroll
      for (int g = 0; g < 4; ++g)
        bs[4 * dm + g] = bx[layer * G4 + g * HH + hc0 + dm] + bh[layer * G4 + g * HH + hc0 + dm];
  }

#pragma unroll 1
  for (int t = 0; t < NSTEP; ++t) {
    const bool act = (layer == 0) ? (t < SS) : (t >= 2);
    f32x4 acc[8];
#pragma unroll
    for (int i = 0; i < 8; ++i) acc[i] = (f32x4){0.f, 0.f, 0.f, 0.f};

    if (act) {
      const _Float16* Ae = (layer == 0) ? x16 + (size_t)t * SLOT
                                        : h1buf + (size_t)((t - 2) & 3) * SLOT;
      const _Float16* aep = Ae + (size_t)l15 * HH + kbase + 8 * lg;
      half8 a[16];
#pragma unroll
      for (int rf = 0; rf < 4; ++rf)
#pragma unroll
        for (int kk = 0; kk < 4; ++kk)
          a[rf * 4 + kk] = *(const half8*)(aep + (size_t)(16 * rf) * HH + 32 * kk);
#pragma unroll
      for (int rf = 0; rf < 4; ++rf)
#pragma unroll
        for (int kk = 0; kk < 4; ++kk) {
          acc[rf * 2 + 0] = __builtin_amdgcn_mfma_f32_16x16x32_f16(a[rf * 4 + kk], Be[kk * 2 + 0], acc[rf * 2 + 0], 0, 0, 0);
          acc[rf * 2 + 1] = __builtin_amdgcn_mfma_f32_16x16x32_f16(a[rf * 4 + kk], Be[kk * 2 + 1], acc[rf * 2 + 1], 0, 0, 0);
        }
    }

    if (tid == 0) {
      wait_ge(bar + SB_GO(grp), (unsigned)t);
      __builtin_amdgcn_fence(__ATOMIC_ACQUIRE, "agent");
    }
    __syncthreads();

    if (act) {
      const _Float16* Ah = (layer == 0) ? h1buf + (size_t)((t - 1) & 3) * SLOT
                                        : h2buf + (size_t)((t - 1) & 1) * SLOT;
      const _Float16* ahp = Ah + (size_t)l15 * HH + kbase + 8 * lg;
      half8 a[16];
#pragma unroll
      for (int rf = 0; rf < 4; ++rf)
#pragma unroll
        for (int kk = 0; kk < 4; ++kk)
          a[rf * 4 + kk] = *(const half8*)(ahp + (size_t)(16 * rf) * HH + 32 * kk);
#pragma unroll
      for (int rf = 0; rf < 4; ++rf)
#pragma unroll
        for (int kk = 0; kk < 4; ++kk) {
          acc[rf * 2 + 0] = __builtin_amdgcn_mfma_f32_16x16x32_f16(a[rf * 4 + kk], Br[kk * 2 + 0], acc[rf * 2 + 0], 0, 0, 0);
          acc[rf * 2 + 1] = __builtin_amdgcn_mfma_f32_16x16x32_f16(a[rf * 4 + kk], Br[kk * 2 + 1], acc[rf * 2 + 1], 0, 0, 0);
        }

#pragma unroll
      for (int rf = 0; rf < 4; ++rf)
#pragma unroll
        for (int c = 0; c < 2; ++c)
          *(f32x4*)&part[w][16 * c + l15][16 * rf + 4 * lg] = acc[rf * 2 + c];
      __syncthreads();

      {
        int col = tid >> 4, rq = tid & 15;
        f32x4 s = {0.f, 0.f, 0.f, 0.f};
#pragma unroll
        for (int ww = 0; ww < 8; ++ww)
          s += *(const f32x4*)&part[ww][col][4 * rq];
        red[4 * rq + 0][col] = s[0];
        red[4 * rq + 1][col] = s[1];
        red[4 * rq + 2][col] = s[2];
        red[4 * rq + 3][col] = s[3];
      }
      __syncthreads();

      if (tid < 256) {
        float v[8];
#pragma unroll
        for (int q = 0; q < 8; ++q) v[q] = red[erow][8 * m2 + q] + bs[q];
        float i0 = sigmf(v[0]), f0 = sigmf(v[1]), g0 = tanhfast(v[2]), o0 = sigmf(v[3]);
        float i1 = sigmf(v[4]), f1 = sigmf(v[5]), g1 = tanhfast(v[6]), o1 = sigmf(v[7]);
        c0 = f0 * c0 + i0 * g0;
        c1 = f1 * c1 + i1 * g1;
        float h0 = tanhfast(c0) * o0;
        float h1 = tanhfast(c1) * o1;
        if (layer == 1) { hm0 = fmaxf(hm0, h0); hm1 = fmaxf(hm1, h1); }
        _Float16* hout = (layer == 0) ? h1buf + (size_t)(t & 3) * SLOT
                                      : h2buf + (size_t)(t & 1) * SLOT;
        unsigned pk = ((unsigned)__builtin_bit_cast(unsigned short, (_Float16)h1) << 16) |
                      (unsigned)__builtin_bit_cast(unsigned short, (_Float16)h0);
        astore((unsigned*)hout + ((erow * HH + hc0) >> 1), pk);
      }
    }

    __syncthreads();
    if (tid == 0) {
      unsigned prev = aadd(bar + SB_ARR(grp));
      if (prev == 32u * (unsigned)(t + 1) - 1u) {
        unsigned p2 = aadd(bar + SB_GLB);
        if (p2 == 8u * (unsigned)(t + 1) - 1u) {
#pragma unroll
          for (int gg = 0; gg < 8; ++gg)
            astore(bar + SB_GO(gg), (unsigned)(t + 1));
        }
      }
    }
  }

  if (layer == 1 && tid < 256) {
    hmax[erow * HH + hc0]     = hm0;
    hmax[erow * HH + hc0 + 1] = hm1;
  }
}

__global__ __launch_bounds__(320) void classify_kernel(const float* __restrict__ hmax,
                                                       const float* __restrict__ Wp,
                                                       const float* __restrict__ bp,
                                                       float* __restrict__ out) {
  int tid = threadIdx.x;  // 320 = 64*5
  int b = tid / 5, jj = tid % 5;
  float s = bp[jj];
  const float* hp = hmax + (size_t)b * HH;
  for (int h = 0; h < HH; ++h) s = fmaf(hp[h], Wp[h * 5 + jj], s);
  out[tid] = s;
}

extern "C" void kernel_launch(void* const* d_in, const int* in_sizes, int n_in,
                              void* d_out, int out_size, void* d_ws, size_t ws_size,
                              hipStream_t stream) {
  const float* inputs = (const float*)d_in[0];
  const float* Wx = (const float*)d_in[1];
  const float* bx = (const float*)d_in[2];
  const float* Wh = (const float*)d_in[3];
  const float* bh = (const float*)d_in[4];
  const float* Wp = (const float*)d_in[5];
  const float* bp = (const float*)d_in[6];
  float* out = (float*)d_out;

  char* ws = (char*)d_ws;
  _Float16* x16 = (_Float16*)(ws + 0);          // 67,108,864
  _Float16* wT  = (_Float16*)(ws + 67108864);   // 33,554,432 -> 100,663,296

  const size_t TRAJ_BYTES = (size_t)513 * 131072;           // 67,239,936
  const size_t NEED_FAST = 100663296ull + 2 * TRAJ_BYTES + 262144 + 8192;  // 235,413,504
  bool fast = ws_size >= NEED_FAST;

  convert_x_kernel<<<32768, 256, 0, stream>>>(inputs, x16);
  convert_w_kernel<<<16384, 256, 0, stream>>>(Wx, Wh, wT);

  if (fast) {
    _Float16* h1traj = (_Float16*)(ws + 100663296);
    _Float16* h2traj = (_Float16*)(ws + 100663296 + TRAJ_BYTES);
    float* hmax = (float*)(ws + 100663296 + 2 * TRAJ_BYTES);
    unsigned* bar = (unsigned*)(ws + 100663296 + 2 * TRAJ_BYTES + 262144);
    hipMemsetAsync(h1traj, 0, 131072, stream);  // zero slot (t = -1)
    hipMemsetAsync(h2traj, 0, 131072, stream);
    hipMemsetAsync(bar, 0, 8192, stream);
    lstm_fused<<<128, 512, 0, stream>>>(x16, wT, bx, bh, h1traj, h2traj, hmax, bar);
    classify_kernel<<<1, 320, 0, stream>>>(hmax, Wp, bp, out);
  } else {
    _Float16* h1buf = (_Float16*)(ws + 100663296);          // 4 slots
    _Float16* h2buf = (_Float16*)(ws + 101187584);          // 2 slots
    float* hmax = (float*)(ws + 101449728);
    unsigned* bar = (unsigned*)(ws + 101711872);
    hipMemsetAsync(h1buf, 0, 524288, stream);
    hipMemsetAsync(h2buf, 0, 262144, stream);
    hipMemsetAsync(bar, 0, 8192, stream);
    lstm_safe<<<256, 512, 0, stream>>>(x16, wT, bx, bh, h1buf, h2buf, hmax, bar);
    classify_kernel<<<1, 320, 0, stream>>>(hmax, Wp, bp, out);
  }
}

// Round 9
// 6233.112 us; speedup vs baseline: 1.3980x; 1.3980x over previous
//
#include <hip/hip_runtime.h>
#include <hip/hip_bf16.h>

typedef _Float16 half8 __attribute__((ext_vector_type(8)));
typedef _Float16 half4v __attribute__((ext_vector_type(4)));
typedef float f32x4 __attribute__((ext_vector_type(4)));

#define BB 64
#define SS 512
#define HH 1024
#define G4 4096
#define SLOT 65536  // elements per 64x1024 fp16 h-slot

// STAGGER barrier: arrive slots s=k&7 at word 32*s; go words per group at 256+32*g
#define AR(s) ((s) * 32)
#define GOW(g) (256 + (g) * 32)
// SAFE-mode (R5 fallback) barrier words
#define SB_ARR(g) ((g) * 32)
#define SB_GLB 256
#define SB_GO(g) (288 + (g) * 32)

__device__ __forceinline__ float sigmf(float x) { return 1.0f / (1.0f + __expf(-x)); }
__device__ __forceinline__ float tanhfast(float x) { return 2.0f / (1.0f + __expf(-2.0f * x)) - 1.0f; }

__device__ __forceinline__ unsigned aload(const unsigned* p) {
  return __hip_atomic_load(p, __ATOMIC_RELAXED, __HIP_MEMORY_SCOPE_AGENT);
}
__device__ __forceinline__ void wait_ge(const unsigned* p, unsigned tgt) {
  while (aload(p) < tgt) __builtin_amdgcn_s_sleep(1);
}
__device__ __forceinline__ unsigned aadd(unsigned* p) {
  return __hip_atomic_fetch_add(p, 1u, __ATOMIC_RELAXED, __HIP_MEMORY_SCOPE_AGENT);
}
__device__ __forceinline__ void astore(unsigned* p, unsigned v) {
  __hip_atomic_store(p, v, __ATOMIC_RELAXED, __HIP_MEMORY_SCOPE_AGENT);
}

// inputs[b][s][h] (f32) -> x16[s][b][h] (fp16), time-major
__global__ __launch_bounds__(256) void convert_x_kernel(const float* __restrict__ in,
                                                        _Float16* __restrict__ x16) {
  size_t idx = (size_t)blockIdx.x * 256 + threadIdx.x;
  int h4 = (int)(idx & 255);
  int s  = (int)((idx >> 8) & 511);
  int b  = (int)(idx >> 17);
  const float4* src = (const float4*)in;
  float4 v = src[((size_t)b * SS + s) * 256 + h4];
  half4v hv = { (_Float16)v.x, (_Float16)v.y, (_Float16)v.z, (_Float16)v.w };
  *(half4v*)(x16 + ((size_t)s * BB + b) * HH + (size_t)h4 * 4) = hv;
}

// W[l][k][n] (f32) -> wT[m][n][k] (fp16); m: 0=Wx l0, 1=Wx l1, 2=Wh l0, 3=Wh l1
__global__ __launch_bounds__(256) void convert_w_kernel(const float* __restrict__ Wx,
                                                        const float* __restrict__ Wh,
                                                        _Float16* __restrict__ wT) {
  __shared__ float tile[32][33];
  int m = blockIdx.x >> 12;
  int t = blockIdx.x & 4095;
  int tn = t & 127, tk = t >> 7;
  int l = m & 1, which = m >> 1;
  const float* src = (which ? Wh : Wx) + (size_t)l * HH * G4;
  int tx = threadIdx.x & 31, ty = threadIdx.x >> 5;
#pragma unroll
  for (int p = 0; p < 4; ++p) {
    int k = tk * 32 + ty + 8 * p, n = tn * 32 + tx;
    tile[ty + 8 * p][tx] = src[(size_t)k * G4 + n];
  }
  __syncthreads();
  _Float16* dst = wT + (size_t)m * G4 * HH;
#pragma unroll
  for (int p = 0; p < 4; ++p) {
    int n = tn * 32 + ty + 8 * p, k = tk * 32 + tx;
    dst[(size_t)n * HH + k] = (_Float16)tile[tx][ty + 8 * p];
  }
}

// One staggered interval. G is a compile-time group id (0..3); CA/CR are the
// prefetched input/recurrent fragments consumed now; NA/NR receive the prefetch
// for interval k+1 (issued last, stays in flight across the next raw barrier).
#define STEP(G, CA, CR, NA, NR)                                                        \
  {                                                                                    \
    const int k = 4 * m + (G);                                                         \
    if (tid == 0 && k >= 3) wait_ge(bar + GOW(grp), (unsigned)(k - 2));                \
    __builtin_amdgcn_s_barrier(); /* raw: prefetch loads stay outstanding */           \
    asm volatile("" ::: "memory");                                                     \
    const bool act = layer ? (m >= 1) : (m < SS);                                      \
    if (act) {                                                                         \
      f32x4 acc0 = {0.f, 0.f, 0.f, 0.f};                                               \
      f32x4 acc1 = {0.f, 0.f, 0.f, 0.f};                                               \
      _Pragma("unroll") for (int kk = 0; kk < 4; ++kk) {                               \
        acc0 = __builtin_amdgcn_mfma_f32_16x16x32_f16(CA[kk], Be[kk * 2 + 0], acc0, 0, 0, 0); \
        acc1 = __builtin_amdgcn_mfma_f32_16x16x32_f16(CA[kk], Be[kk * 2 + 1], acc1, 0, 0, 0); \
      }                                                                                \
      _Pragma("unroll") for (int kk = 0; kk < 4; ++kk) {                               \
        acc0 = __builtin_amdgcn_mfma_f32_16x16x32_f16(CR[kk], Br[kk * 2 + 0], acc0, 0, 0, 0); \
        acc1 = __builtin_amdgcn_mfma_f32_16x16x32_f16(CR[kk], Br[kk * 2 + 1], acc1, 0, 0, 0); \
      }                                                                                \
      *(f32x4*)&part[w][l15][4 * lg] = acc0;                                           \
      *(f32x4*)&part[w][16 + l15][4 * lg] = acc1;                                      \
    }                                                                                  \
    __syncthreads();                                                                   \
    if (act && tid < 128) {                                                            \
      int col = tid >> 2, rq = tid & 3;                                                \
      f32x4 s = {0.f, 0.f, 0.f, 0.f};                                                  \
      _Pragma("unroll") for (int ww = 0; ww < 8; ++ww)                                 \
          s += *(const f32x4*)&part[ww][col][4 * rq];                                  \
      red[4 * rq + 0][col] = s[0];                                                     \
      red[4 * rq + 1][col] = s[1];                                                     \
      red[4 * rq + 2][col] = s[2];                                                     \
      red[4 * rq + 3][col] = s[3];                                                     \
    }                                                                                  \
    __syncthreads();                                                                   \
    if (act && tid < 64) {                                                             \
      float v[8];                                                                      \
      _Pragma("unroll") for (int q = 0; q < 8; ++q) v[q] = red[er][8 * m2 + q] + bs[q];\
      float i0 = sigmf(v[0]), f0 = sigmf(v[1]), g0 = tanhfast(v[2]), o0 = sigmf(v[3]); \
      float i1 = sigmf(v[4]), f1 = sigmf(v[5]), g1 = tanhfast(v[6]), o1 = sigmf(v[7]); \
      float cn0 = f0 * cs0[(G)] + i0 * g0;                                             \
      float cn1 = f1 * cs1[(G)] + i1 * g1;                                             \
      cs0[(G)] = cn0; cs1[(G)] = cn1;                                                  \
      float h0 = tanhfast(cn0) * o0;                                                   \
      float h1 = tanhfast(cn1) * o1;                                                   \
      if (layer == 1) { hx0[(G)] = fmaxf(hx0[(G)], h0); hx1[(G)] = fmaxf(hx1[(G)], h1); } \
      _Float16* hout = (layer == 0) ? h1buf + (size_t)(m + 1) * SLOT                   \
                                    : h2buf + (size_t)m * SLOT;                        \
      int row = 16 * (G) + er;                                                         \
      unsigned pk = ((unsigned)__builtin_bit_cast(unsigned short, (_Float16)h1) << 16) | \
                    (unsigned)__builtin_bit_cast(unsigned short, (_Float16)h0);        \
      astore((unsigned*)hout + ((row * HH + hc0) >> 1), pk);                           \
    }                                                                                  \
    __syncthreads(); /* drains wave-0 publish (vmcnt 0) before arrive */               \
    if (tid == 0) {                                                                    \
      unsigned prev = aadd(bar + AR(k & 7));                                           \
      if (prev == 256u * (unsigned)(k >> 3) + 255u) {                                  \
        _Pragma("unroll") for (int gg = 0; gg < 8; ++gg)                               \
            astore(bar + GOW(gg), (unsigned)(k + 1));                                  \
      }                                                                                \
    }                                                                                  \
    { /* prefetch interval k+1 inputs (gated: data written at k-3, covered by wait) */ \
      const int gn = ((G) + 1) & 3;                                                    \
      const int mn = ((G) == 3) ? m + 1 : m;                                           \
      if (layer == 0) {                                                                \
        if (mn < SS) {                                                                 \
          const _Float16* pa = x16 + (size_t)mn * SLOT + (size_t)(16 * gn + l15) * HH + kbase + 8 * lg;   \
          const _Float16* pr = h1buf + (size_t)mn * SLOT + (size_t)(16 * gn + l15) * HH + kbase + 8 * lg; \
          _Pragma("unroll") for (int kk = 0; kk < 4; ++kk) {                           \
            NA[kk] = *(const half8*)(pa + 32 * kk);                                    \
            NR[kk] = *(const half8*)(pr + 32 * kk);                                    \
          }                                                                            \
        }                                                                              \
      } else {                                                                         \
        if (mn >= 1 && mn <= SS) {                                                     \
          const _Float16* pa = h1buf + (size_t)mn * SLOT + (size_t)(16 * gn + l15) * HH + kbase + 8 * lg;       \
          const _Float16* pr = h2buf + (size_t)(mn - 1) * SLOT + (size_t)(16 * gn + l15) * HH + kbase + 8 * lg; \
          _Pragma("unroll") for (int kk = 0; kk < 4; ++kk) {                           \
            NA[kk] = *(const half8*)(pa + 32 * kk);                                    \
            NR[kk] = *(const half8*)(pr + 32 * kk);                                    \
          }                                                                            \
        }                                                                              \
      }                                                                                \
    }                                                                                  \
  }

// Batch-staggered persistent LSTM: 256 blocks x 512 threads, 1 block/CU.
// Blocks 0..127: layer1; 128..255: layer2. Batch split into 4 groups x 16 rows;
// interval k=4m+g: L1 does group g step m, L2 does group g step m-1.
// Group recurrence spans 4 intervals; wait at k requires release(k-3) -> the
// publish/arrive/release/detect chain hides behind ~3 intervals of other groups.
// Barrier: 8 arrival slots (k&7, spread<=3<8 so one interval per slot at a time);
// finisher (cumulative prev == 256*(k>>3)+255) fans out go=k+1 to 8 group words.
// Trajectory h slots = freshness-by-construction (no acquire fences, R5-proven).
__global__ __launch_bounds__(512, 2) void lstm_stagger(
    const _Float16* __restrict__ x16, const _Float16* __restrict__ wT,
    const float* __restrict__ bx, const float* __restrict__ bh,
    _Float16* __restrict__ h1buf, _Float16* __restrict__ h2buf,
    float* __restrict__ hmax, unsigned* __restrict__ bar) {
  __shared__ float part[8][32][20];  // [wave][col][row+pad] = 20,480 B
  __shared__ float red[16][36];      // [row][col+pad]       =  2,304 B

  const int bid = blockIdx.x;        // 0..255
  const int layer = bid >> 7;
  const int j = bid & 127;           // h-cols [8j, 8j+8)
  const int grp = bid & 7;
  const int tid = threadIdx.x;
  const int w = tid >> 6, l = tid & 63;
  const int l15 = l & 15, lg = l >> 4;

  // one-time: weight fragments into registers (8 waves x K-slice 128)
  const _Float16* wTe = wT + (size_t)layer * G4 * HH;        // Wx of this layer
  const _Float16* wTr = wT + (size_t)(2 + layer) * G4 * HH;  // Wh of this layer
  const int kbase = w * 128;
  half8 Be[8], Br[8];
#pragma unroll
  for (int kk = 0; kk < 4; ++kk)
#pragma unroll
    for (int c = 0; c < 2; ++c) {
      int nl = 16 * c + l15;
      size_t gcol = (size_t)((nl & 3) * HH + 8 * j + (nl >> 2));
      Be[kk * 2 + c] = *(const half8*)(wTe + gcol * HH + kbase + 32 * kk + 8 * lg);
      Br[kk * 2 + c] = *(const half8*)(wTr + gcol * HH + kbase + 32 * kk + 8 * lg);
    }

  // epilogue state (lanes tid<64: row er in group, cols hc0..hc0+1); per-group c/hmax
  const int er = tid >> 2, m2 = tid & 3;
  const int hc0 = 8 * j + 2 * m2;
  float bs[8];
#pragma unroll
  for (int dm = 0; dm < 2; ++dm)
#pragma unroll
    for (int g = 0; g < 4; ++g)
      bs[4 * dm + g] = bx[layer * G4 + g * HH + hc0 + dm] + bh[layer * G4 + g * HH + hc0 + dm];
  float cs0[4] = {0.f, 0.f, 0.f, 0.f}, cs1[4] = {0.f, 0.f, 0.f, 0.f};
  float hx0[4] = {-2.f, -2.f, -2.f, -2.f}, hx1[4] = {-2.f, -2.f, -2.f, -2.f};

  // double-buffered prefetch registers (even g -> p0, odd g -> p1; statically indexed)
  half8 p0A[4], p0R[4], p1A[4], p1R[4];
  if (layer == 0) {  // prologue: interval 0 inputs (x[0] group 0; h1 slot 0 = zeros)
    const _Float16* pa = x16 + (size_t)l15 * HH + kbase + 8 * lg;
    const _Float16* pr = h1buf + (size_t)l15 * HH + kbase + 8 * lg;
#pragma unroll
    for (int kk = 0; kk < 4; ++kk) {
      p0A[kk] = *(const half8*)(pa + 32 * kk);
      p0R[kk] = *(const half8*)(pr + 32 * kk);
    }
  }

#pragma unroll 1
  for (int m = 0; m <= SS; ++m) {
    STEP(0, p0A, p0R, p1A, p1R)
    STEP(1, p1A, p1R, p0A, p0R)
    STEP(2, p0A, p0R, p1A, p1R)
    STEP(3, p1A, p1R, p0A, p0R)
  }

  if (layer == 1 && tid < 64) {
#pragma unroll
    for (int g = 0; g < 4; ++g) {
      int row = 16 * g + er;
      hmax[row * HH + hc0]     = hx0[g];
      hmax[row * HH + hc0 + 1] = hx1[g];
    }
  }
}

// SAFE fallback (round-5 proven, 256 blocks, rings + per-step acquire fence).
__global__ __launch_bounds__(512, 2) void lstm_safe(
    const _Float16* __restrict__ x16, const _Float16* __restrict__ wT,
    const float* __restrict__ bx, const float* __restrict__ bh,
    _Float16* __restrict__ h1buf, _Float16* __restrict__ h2buf,
    float* __restrict__ hmax, unsigned* __restrict__ bar) {
  __shared__ float part[8][32][72];
  __shared__ float red[64][37];

  const int bid = blockIdx.x;
  const int layer = bid >> 7;
  const int j = bid & 127;
  const int tid = threadIdx.x;
  const int w = tid >> 6, l = tid & 63;
  const int l15 = l & 15, lg = l >> 4;
  const int grp = bid & 7;

  const _Float16* wTe = wT + (size_t)layer * G4 * HH;
  const _Float16* wTr = wT + (size_t)(2 + layer) * G4 * HH;
  const int kbase = w * 128;
  half8 Be[8], Br[8];
#pragma unroll
  for (int kk = 0; kk < 4; ++kk)
#pragma unroll
    for (int c = 0; c < 2; ++c) {
      int nl = 16 * c + l15;
      size_t gcol = (size_t)((nl & 3) * HH + 8 * j + (nl >> 2));
      Be[kk * 2 + c] = *(const half8*)(wTe + gcol * HH + kbase + 32 * kk + 8 * lg);
      Br[kk * 2 + c] = *(const half8*)(wTr + gcol * HH + kbase + 32 * kk + 8 * lg);
    }

  const int erow = tid >> 2, m2 = tid & 3;
  const int hc0 = 8 * j + 2 * m2;
  float bs[8];
  float c0 = 0.f, c1 = 0.f, hm0 = -2.f, hm1 = -2.f;
  if (tid < 256) {
#pragma unroll
    for (int dm = 0; dm < 2; ++dm)
#pragma unroll
      for (int g = 0; g < 4; ++g)
        bs[4 * dm + g] = bx[layer * G4 + g * HH + hc0 + dm] + bh[layer * G4 + g * HH + hc0 + dm];
  }

#pragma unroll 1
  for (int t = 0; t < SS + 2; ++t) {
    const bool act = (layer == 0) ? (t < SS) : (t >= 2);
    f32x4 acc[8];
#pragma unroll
    for (int i = 0; i < 8; ++i) acc[i] = (f32x4){0.f, 0.f, 0.f, 0.f};

    if (act) {
      const _Float16* Ae = (layer == 0) ? x16 + (size_t)t * SLOT
                                        : h1buf + (size_t)((t - 2) & 3) * SLOT;
      const _Float16* aep = Ae + (size_t)l15 * HH + kbase + 8 * lg;
      half8 a[16];
#pragma unroll
      for (int rf = 0; rf < 4; ++rf)
#pragma unroll
        for (int kk = 0; kk < 4; ++kk)
          a[rf * 4 + kk] = *(const half8*)(aep + (size_t)(16 * rf) * HH + 32 * kk);
#pragma unroll
      for (int rf = 0; rf < 4; ++rf)
#pragma unroll
        for (int kk = 0; kk < 4; ++kk) {
          acc[rf * 2 + 0] = __builtin_amdgcn_mfma_f32_16x16x32_f16(a[rf * 4 + kk], Be[kk * 2 + 0], acc[rf * 2 + 0], 0, 0, 0);
          acc[rf * 2 + 1] = __builtin_amdgcn_mfma_f32_16x16x32_f16(a[rf * 4 + kk], Be[kk * 2 + 1], acc[rf * 2 + 1], 0, 0, 0);
        }
    }

    if (tid == 0) {
      wait_ge(bar + SB_GO(grp), (unsigned)t);
      __builtin_amdgcn_fence(__ATOMIC_ACQUIRE, "agent");
    }
    __syncthreads();

    if (act) {
      const _Float16* Ah = (layer == 0) ? h1buf + (size_t)((t - 1) & 3) * SLOT
                                        : h2buf + (size_t)((t - 1) & 1) * SLOT;
      const _Float16* ahp = Ah + (size_t)l15 * HH + kbase + 8 * lg;
      half8 a[16];
#pragma unroll
      for (int rf = 0; rf < 4; ++rf)
#pragma unroll
        for (int kk = 0; kk < 4; ++kk)
          a[rf * 4 + kk] = *(const half8*)(ahp + (size_t)(16 * rf) * HH + 32 * kk);
#pragma unroll
      for (int rf = 0; rf < 4; ++rf)
#pragma unroll
        for (int kk = 0; kk < 4; ++kk) {
          acc[rf * 2 + 0] = __builtin_amdgcn_mfma_f32_16x16x32_f16(a[rf * 4 + kk], Br[kk * 2 + 0], acc[rf * 2 + 0], 0, 0, 0);
          acc[rf * 2 + 1] = __builtin_amdgcn_mfma_f32_16x16x32_f16(a[rf * 4 + kk], Br[kk * 2 + 1], acc[rf * 2 + 1], 0, 0, 0);
        }

#pragma unroll
      for (int rf = 0; rf < 4; ++rf)
#pragma unroll
        for (int c = 0; c < 2; ++c)
          *(f32x4*)&part[w][16 * c + l15][16 * rf + 4 * lg] = acc[rf * 2 + c];
      __syncthreads();

      {
        int col = tid >> 4, rq = tid & 15;
        f32x4 s = {0.f, 0.f, 0.f, 0.f};
#pragma unroll
        for (int ww = 0; ww < 8; ++ww)
          s += *(const f32x4*)&part[ww][col][4 * rq];
        red[4 * rq + 0][col] = s[0];
        red[4 * rq + 1][col] = s[1];
        red[4 * rq + 2][col] = s[2];
        red[4 * rq + 3][col] = s[3];
      }
      __syncthreads();

      if (tid < 256) {
        float v[8];
#pragma unroll
        for (int q = 0; q < 8; ++q) v[q] = red[erow][8 * m2 + q] + bs[q];
        float i0 = sigmf(v[0]), f0 = sigmf(v[1]), g0 = tanhfast(v[2]), o0 = sigmf(v[3]);
        float i1 = sigmf(v[4]), f1 = sigmf(v[5]), g1 = tanhfast(v[6]), o1 = sigmf(v[7]);
        c0 = f0 * c0 + i0 * g0;
        c1 = f1 * c1 + i1 * g1;
        float h0 = tanhfast(c0) * o0;
        float h1 = tanhfast(c1) * o1;
        if (layer == 1) { hm0 = fmaxf(hm0, h0); hm1 = fmaxf(hm1, h1); }
        _Float16* hout = (layer == 0) ? h1buf + (size_t)(t & 3) * SLOT
                                      : h2buf + (size_t)(t & 1) * SLOT;
        unsigned pk = ((unsigned)__builtin_bit_cast(unsigned short, (_Float16)h1) << 16) |
                      (unsigned)__builtin_bit_cast(unsigned short, (_Float16)h0);
        astore((unsigned*)hout + ((erow * HH + hc0) >> 1), pk);
      }
    }

    __syncthreads();
    if (tid == 0) {
      unsigned prev = aadd(bar + SB_ARR(grp));
      if (prev == 32u * (unsigned)(t + 1) - 1u) {
        unsigned p2 = aadd(bar + SB_GLB);
        if (p2 == 8u * (unsigned)(t + 1) - 1u) {
#pragma unroll
          for (int gg = 0; gg < 8; ++gg)
            astore(bar + SB_GO(gg), (unsigned)(t + 1));
        }
      }
    }
  }

  if (layer == 1 && tid < 256) {
    hmax[erow * HH + hc0]     = hm0;
    hmax[erow * HH + hc0 + 1] = hm1;
  }
}

__global__ __launch_bounds__(320) void classify_kernel(const float* __restrict__ hmax,
                                                       const float* __restrict__ Wp,
                                                       const float* __restrict__ bp,
                                                       float* __restrict__ out) {
  int tid = threadIdx.x;  // 320 = 64*5
  int b = tid / 5, jj = tid % 5;
  float s = bp[jj];
  const float* hp = hmax + (size_t)b * HH;
  for (int h = 0; h < HH; ++h) s = fmaf(hp[h], Wp[h * 5 + jj], s);
  out[tid] = s;
}

extern "C" void kernel_launch(void* const* d_in, const int* in_sizes, int n_in,
                              void* d_out, int out_size, void* d_ws, size_t ws_size,
                              hipStream_t stream) {
  const float* inputs = (const float*)d_in[0];
  const float* Wx = (const float*)d_in[1];
  const float* bx = (const float*)d_in[2];
  const float* Wh = (const float*)d_in[3];
  const float* bh = (const float*)d_in[4];
  const float* Wp = (const float*)d_in[5];
  const float* bp = (const float*)d_in[6];
  float* out = (float*)d_out;

  char* ws = (char*)d_ws;
  _Float16* x16 = (_Float16*)(ws + 0);          // 67,108,864
  _Float16* wT  = (_Float16*)(ws + 67108864);   // 33,554,432 -> 100,663,296

  const size_t TRAJ_BYTES = (size_t)513 * 131072;           // 67,239,936
  const size_t NEED_FAST = 100663296ull + 2 * TRAJ_BYTES + 262144 + 8192;  // 235,413,504
  bool fast = ws_size >= NEED_FAST;

  convert_x_kernel<<<32768, 256, 0, stream>>>(inputs, x16);
  convert_w_kernel<<<16384, 256, 0, stream>>>(Wx, Wh, wT);

  if (fast) {
    _Float16* h1traj = (_Float16*)(ws + 100663296);
    _Float16* h2traj = (_Float16*)(ws + 100663296 + TRAJ_BYTES);
    float* hmax = (float*)(ws + 100663296 + 2 * TRAJ_BYTES);
    unsigned* bar = (unsigned*)(ws + 100663296 + 2 * TRAJ_BYTES + 262144);
    hipMemsetAsync(h1traj, 0, 131072, stream);  // zero slot 0 (state at t = -1)
    hipMemsetAsync(h2traj, 0, 131072, stream);
    hipMemsetAsync(bar, 0, 8192, stream);
    lstm_stagger<<<256, 512, 0, stream>>>(x16, wT, bx, bh, h1traj, h2traj, hmax, bar);
    classify_kernel<<<1, 320, 0, stream>>>(hmax, Wp, bp, out);
  } else {
    _Float16* h1buf = (_Float16*)(ws + 100663296);          // 4 slots
    _Float16* h2buf = (_Float16*)(ws + 101187584);          // 2 slots
    float* hmax = (float*)(ws + 101449728);
    unsigned* bar = (unsigned*)(ws + 101711872);
    hipMemsetAsync(h1buf, 0, 524288, stream);
    hipMemsetAsync(h2buf, 0, 262144, stream);
    hipMemsetAsync(bar, 0, 8192, stream);
    lstm_safe<<<256, 512, 0, stream>>>(x16, wT, bx, bh, h1buf, h2buf, hmax, bar);
    classify_kernel<<<1, 320, 0, stream>>>(hmax, Wp, bp, out);
  }
}